// Round 2
// baseline (542.529 us; speedup 1.0000x reference)
//
#include <hip/hip_runtime.h>
#include <hip/hip_bf16.h>

#define B_   32
#define HW_  1024
#define C_   512
#define G_   32
#define CG_  16
#define NPIX (B_*HW_)   // 32768

typedef short bf16x8 __attribute__((ext_vector_type(8)));
typedef float f32x4  __attribute__((ext_vector_type(4)));
using bf16 = __hip_bfloat16;

// ---------------- weight transpose + bf16 convert: Wt[d][c] = bf16(w[c][d]) ----
__global__ void wt_kernel(const float* __restrict__ w0, const float* __restrict__ w1,
                          const float* __restrict__ w2, const float* __restrict__ w3,
                          bf16* __restrict__ out) {
    __shared__ float tile[32][33];
    const float* src = blockIdx.z == 0 ? w0 : blockIdx.z == 1 ? w1 : blockIdx.z == 2 ? w2 : w3;
    bf16* dst = out + (size_t)blockIdx.z * C_ * C_;
    int r0 = blockIdx.y * 32, c0 = blockIdx.x * 32;
    int tx = threadIdx.x, ty = threadIdx.y;            // block (32, 8)
    for (int i = 0; i < 32; i += 8)
        tile[ty + i][tx] = src[(size_t)(r0 + ty + i) * C_ + c0 + tx];
    __syncthreads();
    for (int i = 0; i < 32; i += 8)
        dst[(size_t)(c0 + ty + i) * C_ + r0 + tx] = __float2bfloat16(tile[tx][ty + i]);
}

// ---------------- GroupNorm stats: one block per (batch, group) ----------------
__global__ void gn_stats_kernel(const float* __restrict__ x, float* __restrict__ mean,
                                float* __restrict__ rstd) {
    int b = blockIdx.x >> 5, g = blockIdx.x & 31;
    const float* xp = x + (size_t)b * HW_ * C_ + g * CG_;
    float s = 0.f, ss = 0.f;
    for (int p = threadIdx.x; p < HW_; p += 256) {
        const float4* v = (const float4*)(xp + (size_t)p * C_);
        #pragma unroll
        for (int j = 0; j < 4; ++j) {
            float4 t = v[j];
            s  += t.x + t.y + t.z + t.w;
            ss += t.x*t.x + t.y*t.y + t.z*t.z + t.w*t.w;
        }
    }
    #pragma unroll
    for (int off = 32; off; off >>= 1) { s += __shfl_down(s, off); ss += __shfl_down(ss, off); }
    __shared__ float red[2][4];
    int lane = threadIdx.x & 63, wv = threadIdx.x >> 6;
    if (lane == 0) { red[0][wv] = s; red[1][wv] = ss; }
    __syncthreads();
    if (threadIdx.x == 0) {
        float S  = red[0][0] + red[0][1] + red[0][2] + red[0][3];
        float SS = red[1][0] + red[1][1] + red[1][2] + red[1][3];
        const float inv_n = 1.f / (HW_ * CG_);
        float m = S * inv_n;
        float var = SS * inv_n - m * m;
        mean[blockIdx.x] = m;
        rstd[blockIdx.x] = rsqrtf(var + 1e-6f);
    }
}

// ---------------- GroupNorm apply + bf16 convert -------------------------------
__global__ void gn_apply_kernel(const float* __restrict__ x, const float* __restrict__ mean,
                                const float* __restrict__ rstd, const float* __restrict__ gamma,
                                const float* __restrict__ beta, bf16* __restrict__ xn) {
    const size_t n4 = (size_t)NPIX * C_ / 4;
    for (size_t i4 = (size_t)blockIdx.x * blockDim.x + threadIdx.x; i4 < n4;
         i4 += (size_t)gridDim.x * blockDim.x) {
        size_t e = i4 * 4;
        int cc = (int)(e & (C_ - 1));
        int bg = (int)(e >> 19) * G_ + (cc >> 4);   // 2^19 elements per batch
        float m = mean[bg], rs = rstd[bg];
        float4 t = *(const float4*)(x + e);
        __align__(8) bf16 o[4];
        o[0] = __float2bfloat16((t.x - m) * rs * gamma[cc + 0] + beta[cc + 0]);
        o[1] = __float2bfloat16((t.y - m) * rs * gamma[cc + 1] + beta[cc + 1]);
        o[2] = __float2bfloat16((t.z - m) * rs * gamma[cc + 2] + beta[cc + 2]);
        o[3] = __float2bfloat16((t.w - m) * rs * gamma[cc + 3] + beta[cc + 3]);
        *(ushort4*)(xn + e) = *(ushort4*)o;
    }
}

// ---------------- bf16 64x64 tiled transpose (batched): out[c][r] = in[r][c] ---
__global__ void transpose_kernel(const bf16* __restrict__ in, bf16* __restrict__ out,
                                 int R, int Cc) {
    __shared__ bf16 tile[64][65];
    size_t boff = (size_t)blockIdx.z * R * Cc;
    const bf16* src = in + boff;
    bf16* dst = out + boff;
    int c0 = blockIdx.x * 64, r0 = blockIdx.y * 64;
    int tx = threadIdx.x, ty = threadIdx.y;            // block (64, 4)
    for (int i = 0; i < 64; i += 4)
        tile[ty + i][tx] = src[(size_t)(r0 + ty + i) * Cc + c0 + tx];
    __syncthreads();
    for (int i = 0; i < 64; i += 4)
        dst[(size_t)(c0 + ty + i) * R + r0 + tx] = tile[tx][ty + i];
}

// ---------------- row softmax: fp32 in (rows of 1024) -> bf16 out --------------
__global__ void softmax_kernel(const float* __restrict__ S, bf16* __restrict__ P) {
    size_t row = blockIdx.x;
    const float* sp = S + row * 1024;
    float4 t = ((const float4*)sp)[threadIdx.x];
    float mx = fmaxf(fmaxf(t.x, t.y), fmaxf(t.z, t.w));
    #pragma unroll
    for (int off = 1; off < 64; off <<= 1) mx = fmaxf(mx, __shfl_xor(mx, off));
    __shared__ float redm[4], reds[4];
    int lane = threadIdx.x & 63, wv = threadIdx.x >> 6;
    if (lane == 0) redm[wv] = mx;
    __syncthreads();
    mx = fmaxf(fmaxf(redm[0], redm[1]), fmaxf(redm[2], redm[3]));
    float e0 = __expf(t.x - mx), e1 = __expf(t.y - mx);
    float e2 = __expf(t.z - mx), e3 = __expf(t.w - mx);
    float sm = e0 + e1 + e2 + e3;
    #pragma unroll
    for (int off = 1; off < 64; off <<= 1) sm += __shfl_xor(sm, off);
    if (lane == 0) reds[wv] = sm;
    __syncthreads();
    sm = reds[0] + reds[1] + reds[2] + reds[3];
    float inv = 1.f / sm;
    __align__(8) bf16 o[4];
    o[0] = __float2bfloat16(e0 * inv);
    o[1] = __float2bfloat16(e1 * inv);
    o[2] = __float2bfloat16(e2 * inv);
    o[3] = __float2bfloat16(e3 * inv);
    *(ushort4*)(P + row * 1024 + (size_t)threadIdx.x * 4) = *(ushort4*)o;
}

// ---------------- generic batched MFMA GEMM: C[m][n] = sum_k A[m][k]*Bt[n][k] --
// lda == ldb == K, ldc == N. 128x128 tile, BK=32, 4 waves (2x2), 4x4 frags/wave.
// OUT_MODE: 0 bf16, 1 bf16+bias, 2 f32*scale, 3 f32+bias+residual
template<int OUT_MODE>
__global__ __launch_bounds__(256) void gemm_kernel(
    const bf16* __restrict__ A, const bf16* __restrict__ Bt, void* __restrict__ Cv,
    const float* __restrict__ bias, const float* __restrict__ res,
    int M, int N, int K, float scale,
    long long strideA, long long strideB, long long strideC)
{
    __shared__ __align__(16) ushort la[128][40];
    __shared__ __align__(16) ushort lb[128][40];
    const bf16* Ab = A + (size_t)blockIdx.z * strideA;
    const bf16* Bb = Bt + (size_t)blockIdx.z * strideB;
    int m0 = blockIdx.y * 128, n0 = blockIdx.x * 128;
    int t = threadIdx.x;
    int wv = t >> 6, lane = t & 63;
    int wm = wv >> 1, wn = wv & 1;          // 2x2 waves, 64x64 each
    int lrow = lane & 15, kg = lane >> 4;
    int sr = t >> 2, sc = (t & 3) * 8;      // staging: 64 rows x 32 cols per pass, 16B/thread
    f32x4 acc[4][4] = {};

    for (int k0 = 0; k0 < K; k0 += 32) {
        // full 128x32 tile: each thread stages rows sr and sr+64 of both A and B
        *(uint4*)&la[sr][sc]      = *(const uint4*)(Ab + (size_t)(m0 + sr) * K + k0 + sc);
        *(uint4*)&la[sr + 64][sc] = *(const uint4*)(Ab + (size_t)(m0 + sr + 64) * K + k0 + sc);
        *(uint4*)&lb[sr][sc]      = *(const uint4*)(Bb + (size_t)(n0 + sr) * K + k0 + sc);
        *(uint4*)&lb[sr + 64][sc] = *(const uint4*)(Bb + (size_t)(n0 + sr + 64) * K + k0 + sc);
        __syncthreads();
        bf16x8 af[4], bg[4];
        #pragma unroll
        for (int f = 0; f < 4; ++f) {
            af[f] = *(const bf16x8*)&la[wm * 64 + f * 16 + lrow][kg * 8];
            bg[f] = *(const bf16x8*)&lb[wn * 64 + f * 16 + lrow][kg * 8];
        }
        #pragma unroll
        for (int i = 0; i < 4; ++i)
            #pragma unroll
            for (int j = 0; j < 4; ++j)
                acc[i][j] = __builtin_amdgcn_mfma_f32_16x16x32_bf16(af[i], bg[j], acc[i][j], 0, 0, 0);
        __syncthreads();
    }

    int rg = lane >> 4, ccol = lane & 15;
    #pragma unroll
    for (int i = 0; i < 4; ++i)
        #pragma unroll
        for (int j = 0; j < 4; ++j) {
            int gcol = n0 + wn * 64 + j * 16 + ccol;
            int grow_base = m0 + wm * 64 + i * 16 + rg * 4;
            #pragma unroll
            for (int r = 0; r < 4; ++r) {
                size_t idx = (size_t)blockIdx.z * strideC + (size_t)(grow_base + r) * N + gcol;
                float v = acc[i][j][r];
                if (OUT_MODE == 0)      ((bf16*)Cv)[idx] = __float2bfloat16(v);
                else if (OUT_MODE == 1) ((bf16*)Cv)[idx] = __float2bfloat16(v + bias[gcol]);
                else if (OUT_MODE == 2) ((float*)Cv)[idx] = v * scale;
                else                    ((float*)Cv)[idx] = v + bias[gcol] + res[idx];
            }
        }
}

extern "C" void kernel_launch(void* const* d_in, const int* in_sizes, int n_in,
                              void* d_out, int out_size, void* d_ws, size_t ws_size,
                              hipStream_t stream) {
    const float* x     = (const float*)d_in[0];
    const float* gamma = (const float*)d_in[1];
    const float* beta  = (const float*)d_in[2];
    const float* wq    = (const float*)d_in[3];
    const float* bq    = (const float*)d_in[4];
    const float* wk    = (const float*)d_in[5];
    const float* bk    = (const float*)d_in[6];
    const float* wv    = (const float*)d_in[7];
    const float* bv    = (const float*)d_in[8];
    const float* wo    = (const float*)d_in[9];
    const float* bo    = (const float*)d_in[10];
    float* out = (float*)d_out;

    char* ws = (char*)d_ws;
    const size_t MB = 1ull << 20;
    bf16*  Wt   = (bf16*)ws;                    // [0,2) MB: 4x 512x512 bf16 (transposed)
    float* mean = (float*)(ws + 2 * MB);        // [2,4) MB: stats
    float* rstd = mean + 1024;
    bf16*  xn   = (bf16*)(ws + 4 * MB);         // [4,36)
    bf16*  q    = (bf16*)(ws + 36 * MB);        // [36,68)
    bf16*  k    = (bf16*)(ws + 68 * MB);        // [68,100)
    bf16*  v    = (bf16*)(ws + 100 * MB);       // [100,132)
    bf16*  qt   = (bf16*)(ws + 132 * MB);       // [132,164)
    bf16*  kt   = (bf16*)(ws + 164 * MB);       // [164,196)
    float* Sb   = (float*)(ws + 4 * MB);        // alias xn (dead after QKV): 8-batch chunk, 32 MB
    bf16*  P    = (bf16*)(ws + 36 * MB);        // alias q,k (dead after transposes): 64 MB
    bf16*  outr = (bf16*)(ws + 132 * MB);       // alias qt (dead after all S chunks)

    const long long SB = 524288;                // per-batch elements (1024*512)
    const long long SS = 1048576;               // per-batch S/P elements (1024*1024)
    const float scale = 0.04419417382415922f;   // 512^-0.5

    wt_kernel<<<dim3(16, 16, 4), dim3(32, 8), 0, stream>>>(wq, wk, wv, wo, Wt);
    gn_stats_kernel<<<1024, 256, 0, stream>>>(x, mean, rstd);
    gn_apply_kernel<<<4096, 256, 0, stream>>>(x, mean, rstd, gamma, beta, xn);

    // Q/K/V projections: (32768 x 512) @ (512 x 512)
    gemm_kernel<1><<<dim3(4, 256, 1), 256, 0, stream>>>(xn, Wt,               q, bq, nullptr, NPIX, C_, C_, 1.f, 0, 0, 0);
    gemm_kernel<1><<<dim3(4, 256, 1), 256, 0, stream>>>(xn, Wt + 1 * C_ * C_, k, bk, nullptr, NPIX, C_, C_, 1.f, 0, 0, 0);
    gemm_kernel<1><<<dim3(4, 256, 1), 256, 0, stream>>>(xn, Wt + 2 * C_ * C_, v, bv, nullptr, NPIX, C_, C_, 1.f, 0, 0, 0);

    // per-batch flat view (512,1024) -> transposed (1024,512) for S operands
    transpose_kernel<<<dim3(16, 8, 32), dim3(64, 4), 0, stream>>>(q, qt, 512, 1024);
    transpose_kernel<<<dim3(16, 8, 32), dim3(64, 4), 0, stream>>>(k, kt, 512, 1024);

    // S = scale * Qr^T Kr, row-softmax -> P (bf16), chunked 8 batches at a time
    for (int c = 0; c < 4; ++c) {
        gemm_kernel<2><<<dim3(8, 8, 8), 256, 0, stream>>>(
            qt + (size_t)c * 8 * SB, kt + (size_t)c * 8 * SB, Sb, nullptr, nullptr,
            1024, 1024, 512, scale, SB, SB, SS);
        softmax_kernel<<<8192, 256, 0, stream>>>(Sb, P + (size_t)c * 8 * SS);
    }

    // Out_r[i][j1] = sum_j2 Vr[i][j2] * P[j1][j2]   (per batch: 512x1024, K=1024)
    gemm_kernel<0><<<dim3(8, 4, 32), 256, 0, stream>>>(
        v, P, outr, nullptr, nullptr, 512, 1024, 1024, 1.f, SB, SS, SB);

    // final projection + bias + residual, fp32 out
    gemm_kernel<3><<<dim3(4, 256, 1), 256, 0, stream>>>(
        outr, Wt + 3 * C_ * C_, out, bo, x, NPIX, C_, C_, 1.f, 0, 0, 0);
}

// Round 3
// 515.070 us; speedup vs baseline: 1.0533x; 1.0533x over previous
//
#include <hip/hip_runtime.h>
#include <hip/hip_bf16.h>

#define B_   32
#define HW_  1024
#define C_   512
#define G_   32
#define CG_  16
#define NPIX (B_*HW_)   // 32768

typedef short bf16x8 __attribute__((ext_vector_type(8)));
typedef float f32x4  __attribute__((ext_vector_type(4)));
using bf16 = __hip_bfloat16;

// async global->LDS, 16B per lane; LDS dest = wave-uniform base + lane*16
__device__ __forceinline__ void gload16(const void* g, void* l) {
    __builtin_amdgcn_global_load_lds((const __attribute__((address_space(1))) void*)g,
                                     (__attribute__((address_space(3))) void*)l, 16, 0, 0);
}

// ---------------- weight transpose + bf16 convert: Wt[d][c] = bf16(w[c][d]) ----
__global__ void wt_kernel(const float* __restrict__ w0, const float* __restrict__ w1,
                          const float* __restrict__ w2, const float* __restrict__ w3,
                          bf16* __restrict__ out) {
    __shared__ float tile[32][33];
    const float* src = blockIdx.z == 0 ? w0 : blockIdx.z == 1 ? w1 : blockIdx.z == 2 ? w2 : w3;
    bf16* dst = out + (size_t)blockIdx.z * C_ * C_;
    int r0 = blockIdx.y * 32, c0 = blockIdx.x * 32;
    int tx = threadIdx.x, ty = threadIdx.y;            // block (32, 8)
    for (int i = 0; i < 32; i += 8)
        tile[ty + i][tx] = src[(size_t)(r0 + ty + i) * C_ + c0 + tx];
    __syncthreads();
    for (int i = 0; i < 32; i += 8)
        dst[(size_t)(c0 + ty + i) * C_ + r0 + tx] = __float2bfloat16(tile[tx][ty + i]);
}

// ---------------- concat bias: [bq | bk | bv] -> 1536 floats -------------------
__global__ void biascat_kernel(const float* __restrict__ bq, const float* __restrict__ bk,
                               const float* __restrict__ bv, float* __restrict__ o) {
    int i = blockIdx.x * 256 + threadIdx.x;            // grid 6 x 256
    const float* s = i < 512 ? bq : i < 1024 ? bk : bv;
    o[i] = s[i & 511];
}

// ---------------- GroupNorm stats: one block per (batch, group) ----------------
__global__ void gn_stats_kernel(const float* __restrict__ x, float* __restrict__ mean,
                                float* __restrict__ rstd) {
    int b = blockIdx.x >> 5, g = blockIdx.x & 31;
    const float* xp = x + (size_t)b * HW_ * C_ + g * CG_;
    float s = 0.f, ss = 0.f;
    for (int p = threadIdx.x; p < HW_; p += 256) {
        const float4* v = (const float4*)(xp + (size_t)p * C_);
        #pragma unroll
        for (int j = 0; j < 4; ++j) {
            float4 t = v[j];
            s  += t.x + t.y + t.z + t.w;
            ss += t.x*t.x + t.y*t.y + t.z*t.z + t.w*t.w;
        }
    }
    #pragma unroll
    for (int off = 32; off; off >>= 1) { s += __shfl_down(s, off); ss += __shfl_down(ss, off); }
    __shared__ float red[2][4];
    int lane = threadIdx.x & 63, wv = threadIdx.x >> 6;
    if (lane == 0) { red[0][wv] = s; red[1][wv] = ss; }
    __syncthreads();
    if (threadIdx.x == 0) {
        float S  = red[0][0] + red[0][1] + red[0][2] + red[0][3];
        float SS = red[1][0] + red[1][1] + red[1][2] + red[1][3];
        const float inv_n = 1.f / (HW_ * CG_);
        float m = S * inv_n;
        float var = SS * inv_n - m * m;
        mean[blockIdx.x] = m;
        rstd[blockIdx.x] = rsqrtf(var + 1e-6f);
    }
}

// ---------------- GroupNorm apply + bf16 convert -------------------------------
__global__ void gn_apply_kernel(const float* __restrict__ x, const float* __restrict__ mean,
                                const float* __restrict__ rstd, const float* __restrict__ gamma,
                                const float* __restrict__ beta, bf16* __restrict__ xn) {
    const size_t n4 = (size_t)NPIX * C_ / 4;
    for (size_t i4 = (size_t)blockIdx.x * blockDim.x + threadIdx.x; i4 < n4;
         i4 += (size_t)gridDim.x * blockDim.x) {
        size_t e = i4 * 4;
        int cc = (int)(e & (C_ - 1));
        int bg = (int)(e >> 19) * G_ + (cc >> 4);   // 2^19 elements per batch
        float m = mean[bg], rs = rstd[bg];
        float4 t = *(const float4*)(x + e);
        __align__(8) bf16 o[4];
        o[0] = __float2bfloat16((t.x - m) * rs * gamma[cc + 0] + beta[cc + 0]);
        o[1] = __float2bfloat16((t.y - m) * rs * gamma[cc + 1] + beta[cc + 1]);
        o[2] = __float2bfloat16((t.z - m) * rs * gamma[cc + 2] + beta[cc + 2]);
        o[3] = __float2bfloat16((t.w - m) * rs * gamma[cc + 3] + beta[cc + 3]);
        *(ushort4*)(xn + e) = *(ushort4*)o;
    }
}

// ---------------- bf16 64x64 tiled transpose (batched): out[c][r] = in[r][c] ---
__global__ void transpose_kernel(const bf16* __restrict__ in, bf16* __restrict__ out,
                                 int R, int Cc) {
    __shared__ bf16 tile[64][65];
    size_t boff = (size_t)blockIdx.z * R * Cc;
    const bf16* src = in + boff;
    bf16* dst = out + boff;
    int c0 = blockIdx.x * 64, r0 = blockIdx.y * 64;
    int tx = threadIdx.x, ty = threadIdx.y;            // block (64, 4)
    for (int i = 0; i < 64; i += 4)
        tile[ty + i][tx] = src[(size_t)(r0 + ty + i) * Cc + c0 + tx];
    __syncthreads();
    for (int i = 0; i < 64; i += 4)
        dst[(size_t)(c0 + ty + i) * R + r0 + tx] = tile[tx][ty + i];
}

// ---------------- row softmax: fp32 in (rows of 1024) -> bf16 out --------------
__global__ void softmax_kernel(const float* __restrict__ S, bf16* __restrict__ P) {
    size_t row = blockIdx.x;
    const float* sp = S + row * 1024;
    float4 t = ((const float4*)sp)[threadIdx.x];
    float mx = fmaxf(fmaxf(t.x, t.y), fmaxf(t.z, t.w));
    #pragma unroll
    for (int off = 1; off < 64; off <<= 1) mx = fmaxf(mx, __shfl_xor(mx, off));
    __shared__ float redm[4], reds[4];
    int lane = threadIdx.x & 63, wv = threadIdx.x >> 6;
    if (lane == 0) redm[wv] = mx;
    __syncthreads();
    mx = fmaxf(fmaxf(redm[0], redm[1]), fmaxf(redm[2], redm[3]));
    float e0 = __expf(t.x - mx), e1 = __expf(t.y - mx);
    float e2 = __expf(t.z - mx), e3 = __expf(t.w - mx);
    float sm = e0 + e1 + e2 + e3;
    #pragma unroll
    for (int off = 1; off < 64; off <<= 1) sm += __shfl_xor(sm, off);
    if (lane == 0) reds[wv] = sm;
    __syncthreads();
    sm = reds[0] + reds[1] + reds[2] + reds[3];
    float inv = 1.f / sm;
    __align__(8) bf16 o[4];
    o[0] = __float2bfloat16(e0 * inv);
    o[1] = __float2bfloat16(e1 * inv);
    o[2] = __float2bfloat16(e2 * inv);
    o[3] = __float2bfloat16(e3 * inv);
    *(ushort4*)(P + row * 1024 + (size_t)threadIdx.x * 4) = *(ushort4*)o;
}

// ---------------- batched MFMA GEMM, m97 structure -----------------------------
// C[m][n] = sum_k A[m][k] * Bt[n][k].  128x128 tile, BK=32, 4 waves (2x2).
// global_load_lds width-16 staging into LINEAR LDS [128][32] with source-side
// XOR slot swizzle (slot ^= row&3) + matching swizzled ds_read (rule 21).
// Grid total MUST be a multiple of 8 (bijective XCD swizzle).
// OUT_MODE: 0 bf16, 2 f32*scale, 3 f32+bias+residual, 4 fused-QKV bf16+bias
template<int OUT_MODE>
__global__ __launch_bounds__(256) void gemm_kernel(
    const bf16* __restrict__ A, const bf16* __restrict__ Bt, void* __restrict__ Cv,
    const float* __restrict__ bias, const float* __restrict__ res,
    int M, int N, int K, float scale,
    long long strideA, long long strideB, long long strideC)
{
    __shared__ __align__(16) ushort la[128 * 32];
    __shared__ __align__(16) ushort lb[128 * 32];

    // bijective XCD swizzle: each XCD gets a contiguous orig-range, n fastest
    int gx = gridDim.x, gy = gridDim.y;
    int nwg = gx * gy * (int)gridDim.z;
    int d = blockIdx.x + gx * (blockIdx.y + gy * blockIdx.z);
    int orig = (d & 7) * (nwg >> 3) + (d >> 3);
    int bx = orig % gx, rest = orig / gx;
    int by = rest % gy, bz = rest / gy;

    const bf16* Ab = A + (size_t)bz * strideA;
    const bf16* Bb = Bt + (size_t)bz * strideB;
    int m0 = by * 128, n0 = bx * 128;
    int t = threadIdx.x;
    int wv = t >> 6, lane = t & 63;
    int wm = wv >> 1, wn = wv & 1;          // 2x2 waves, 64x64 each
    int lrow = lane & 15, kg = lane >> 4;
    int slot8 = (kg ^ (lrow & 3)) << 3;     // swizzled read slot (ushorts)

    // staging: wave wv stages chunks {2wv, 2wv+1} (16 rows each) of A and B
    int srow = lane >> 2;                   // row within chunk
    int gslot = (lane & 3) ^ (srow & 3);    // inverse-swizzled global k-slot
    long long arow0 = (long long)(m0 + wv * 32 + srow) * K + gslot * 8;
    long long brow0 = (long long)(n0 + wv * 32 + srow) * K + gslot * 8;

    f32x4 acc[4][4] = {};

    for (int k0 = 0; k0 < K; k0 += 32) {
        #pragma unroll
        for (int cc = 0; cc < 2; ++cc) {
            gload16(Ab + arow0 + (long long)cc * 16 * K + k0, (char*)la + (wv * 2 + cc) * 1024);
            gload16(Bb + brow0 + (long long)cc * 16 * K + k0, (char*)lb + (wv * 2 + cc) * 1024);
        }
        __syncthreads();
        bf16x8 af[4], bg[4];
        #pragma unroll
        for (int f = 0; f < 4; ++f) {
            af[f] = *(const bf16x8*)&la[(wm * 64 + f * 16 + lrow) * 32 + slot8];
            bg[f] = *(const bf16x8*)&lb[(wn * 64 + f * 16 + lrow) * 32 + slot8];
        }
        #pragma unroll
        for (int i = 0; i < 4; ++i)
            #pragma unroll
            for (int j = 0; j < 4; ++j)
                acc[i][j] = __builtin_amdgcn_mfma_f32_16x16x32_bf16(af[i], bg[j], acc[i][j], 0, 0, 0);
        __syncthreads();
    }

    int rg = lane >> 4, ccol = lane & 15;
    #pragma unroll
    for (int i = 0; i < 4; ++i)
        #pragma unroll
        for (int j = 0; j < 4; ++j) {
            int gcol = n0 + wn * 64 + j * 16 + ccol;
            int grow_base = m0 + wm * 64 + i * 16 + rg * 4;
            #pragma unroll
            for (int r = 0; r < 4; ++r) {
                float v = acc[i][j][r];
                if (OUT_MODE == 4) {
                    // fused QKV: col 0-511 -> q, 512-1023 -> k, 1024-1535 -> v
                    size_t idx = (size_t)(gcol >> 9) * ((size_t)NPIX * C_)
                               + (size_t)(grow_base + r) * C_ + (gcol & 511);
                    ((bf16*)Cv)[idx] = __float2bfloat16(v + bias[gcol]);
                } else {
                    size_t idx = (size_t)bz * strideC + (size_t)(grow_base + r) * N + gcol;
                    if (OUT_MODE == 0)      ((bf16*)Cv)[idx] = __float2bfloat16(v);
                    else if (OUT_MODE == 2) ((float*)Cv)[idx] = v * scale;
                    else                    ((float*)Cv)[idx] = v + bias[gcol] + res[idx];
                }
            }
        }
}

extern "C" void kernel_launch(void* const* d_in, const int* in_sizes, int n_in,
                              void* d_out, int out_size, void* d_ws, size_t ws_size,
                              hipStream_t stream) {
    const float* x     = (const float*)d_in[0];
    const float* gamma = (const float*)d_in[1];
    const float* beta  = (const float*)d_in[2];
    const float* wq    = (const float*)d_in[3];
    const float* bq    = (const float*)d_in[4];
    const float* wk    = (const float*)d_in[5];
    const float* bk    = (const float*)d_in[6];
    const float* wv    = (const float*)d_in[7];
    const float* bv    = (const float*)d_in[8];
    const float* wo    = (const float*)d_in[9];
    const float* bo    = (const float*)d_in[10];
    float* out = (float*)d_out;

    char* ws = (char*)d_ws;
    const size_t MB = 1ull << 20;
    bf16*  Wt   = (bf16*)ws;                    // [0,2) MB: 4x 512x512 bf16 (transposed)
    float* mean = (float*)(ws + 2 * MB);        // stats
    float* rstd = mean + 1024;
    float* bqkv = (float*)(ws + 2 * MB + 16384);// 1536 floats fused bias
    bf16*  xn   = (bf16*)(ws + 4 * MB);         // [4,36)
    bf16*  q    = (bf16*)(ws + 36 * MB);        // [36,68)   } q,k,v contiguous
    bf16*  k    = (bf16*)(ws + 68 * MB);        // [68,100)  } (fused QKV writes
    bf16*  v    = (bf16*)(ws + 100 * MB);       // [100,132) }  all three)
    bf16*  qt   = (bf16*)(ws + 132 * MB);       // [132,164)
    bf16*  kt   = (bf16*)(ws + 164 * MB);       // [164,196)
    float* Sb   = (float*)(ws + 4 * MB);        // alias xn (dead after QKV)
    bf16*  P    = (bf16*)(ws + 36 * MB);        // alias q,k (dead after transposes)
    bf16*  outr = (bf16*)(ws + 132 * MB);       // alias qt (dead after S chunks)

    const long long SB = 524288;                // per-batch elements (1024*512)
    const long long SS = 1048576;               // per-batch S/P elements
    const float scale = 0.04419417382415922f;   // 512^-0.5

    wt_kernel<<<dim3(16, 16, 4), dim3(32, 8), 0, stream>>>(wq, wk, wv, wo, Wt);
    biascat_kernel<<<6, 256, 0, stream>>>(bq, bk, bv, bqkv);
    gn_stats_kernel<<<1024, 256, 0, stream>>>(x, mean, rstd);
    gn_apply_kernel<<<4096, 256, 0, stream>>>(x, mean, rstd, gamma, beta, xn);

    // fused QKV projection: (32768 x 512) @ (512 x 1536), split-writes q,k,v
    gemm_kernel<4><<<dim3(12, 256, 1), 256, 0, stream>>>(
        xn, Wt, q, bqkv, nullptr, NPIX, 1536, C_, 1.f, 0, 0, 0);

    // per-batch flat view (512,1024) -> transposed (1024,512) for S operands
    transpose_kernel<<<dim3(16, 8, 32), dim3(64, 4), 0, stream>>>(q, qt, 512, 1024);
    transpose_kernel<<<dim3(16, 8, 32), dim3(64, 4), 0, stream>>>(k, kt, 512, 1024);

    // S = scale * Qr^T Kr, row-softmax -> P (bf16), chunked 8 batches at a time
    for (int c = 0; c < 4; ++c) {
        gemm_kernel<2><<<dim3(8, 8, 8), 256, 0, stream>>>(
            qt + (size_t)c * 8 * SB, kt + (size_t)c * 8 * SB, Sb, nullptr, nullptr,
            1024, 1024, 512, scale, SB, SB, SS);
        softmax_kernel<<<8192, 256, 0, stream>>>(Sb, P + (size_t)c * 8 * SS);
    }

    // Out_r[i][j1] = sum_j2 Vr[i][j2] * P[j1][j2]   (per batch: 512x1024, K=1024)
    gemm_kernel<0><<<dim3(8, 4, 32), 256, 0, stream>>>(
        v, P, outr, nullptr, nullptr, 512, 1024, 1024, 1.f, SB, SS, SB);

    // final projection + bias + residual, fp32 out
    gemm_kernel<3><<<dim3(4, 256, 1), 256, 0, stream>>>(
        outr, Wt + 3 * C_ * C_, out, bo, x, NPIX, C_, C_, 1.f, 0, 0, 0);
}

// Round 4
// 449.705 us; speedup vs baseline: 1.2064x; 1.1454x over previous
//
#include <hip/hip_runtime.h>
#include <hip/hip_bf16.h>

#define B_   32
#define HW_  1024
#define C_   512
#define G_   32
#define CG_  16
#define NPIX (B_*HW_)   // 32768

typedef short bf16x8 __attribute__((ext_vector_type(8)));
typedef float f32x4  __attribute__((ext_vector_type(4)));
using bf16 = __hip_bfloat16;

// async global->LDS, 16B per lane; LDS dest = wave-uniform base + lane*16
__device__ __forceinline__ void gload16(const void* g, void* l) {
    __builtin_amdgcn_global_load_lds((const __attribute__((address_space(1))) void*)g,
                                     (__attribute__((address_space(3))) void*)l, 16, 0, 0);
}

// ---------------- weight transpose + bf16 convert: Wt[d][c] = bf16(w[c][d]) ----
__global__ void wt_kernel(const float* __restrict__ w0, const float* __restrict__ w1,
                          const float* __restrict__ w2, const float* __restrict__ w3,
                          bf16* __restrict__ out) {
    __shared__ float tile[32][33];
    const float* src = blockIdx.z == 0 ? w0 : blockIdx.z == 1 ? w1 : blockIdx.z == 2 ? w2 : w3;
    bf16* dst = out + (size_t)blockIdx.z * C_ * C_;
    int r0 = blockIdx.y * 32, c0 = blockIdx.x * 32;
    int tx = threadIdx.x, ty = threadIdx.y;            // block (32, 8)
    for (int i = 0; i < 32; i += 8)
        tile[ty + i][tx] = src[(size_t)(r0 + ty + i) * C_ + c0 + tx];
    __syncthreads();
    for (int i = 0; i < 32; i += 8)
        dst[(size_t)(c0 + ty + i) * C_ + r0 + tx] = __float2bfloat16(tile[tx][ty + i]);
}

// ---------------- concat bias: [bq | bk | bv] -> 1536 floats -------------------
__global__ void biascat_kernel(const float* __restrict__ bq, const float* __restrict__ bk,
                               const float* __restrict__ bv, float* __restrict__ o) {
    int i = blockIdx.x * 256 + threadIdx.x;            // grid 6 x 256
    const float* s = i < 512 ? bq : i < 1024 ? bk : bv;
    o[i] = s[i & 511];
}

// ---------------- GroupNorm stats: one block per (batch, group) ----------------
__global__ void gn_stats_kernel(const float* __restrict__ x, float* __restrict__ mean,
                                float* __restrict__ rstd) {
    int b = blockIdx.x >> 5, g = blockIdx.x & 31;
    const float* xp = x + (size_t)b * HW_ * C_ + g * CG_;
    float s = 0.f, ss = 0.f;
    for (int p = threadIdx.x; p < HW_; p += 256) {
        const float4* v = (const float4*)(xp + (size_t)p * C_);
        #pragma unroll
        for (int j = 0; j < 4; ++j) {
            float4 t = v[j];
            s  += t.x + t.y + t.z + t.w;
            ss += t.x*t.x + t.y*t.y + t.z*t.z + t.w*t.w;
        }
    }
    #pragma unroll
    for (int off = 32; off; off >>= 1) { s += __shfl_down(s, off); ss += __shfl_down(ss, off); }
    __shared__ float red[2][4];
    int lane = threadIdx.x & 63, wv = threadIdx.x >> 6;
    if (lane == 0) { red[0][wv] = s; red[1][wv] = ss; }
    __syncthreads();
    if (threadIdx.x == 0) {
        float S  = red[0][0] + red[0][1] + red[0][2] + red[0][3];
        float SS = red[1][0] + red[1][1] + red[1][2] + red[1][3];
        const float inv_n = 1.f / (HW_ * CG_);
        float m = S * inv_n;
        float var = SS * inv_n - m * m;
        mean[blockIdx.x] = m;
        rstd[blockIdx.x] = rsqrtf(var + 1e-6f);
    }
}

// ---------------- GroupNorm apply + bf16 convert -------------------------------
__global__ void gn_apply_kernel(const float* __restrict__ x, const float* __restrict__ mean,
                                const float* __restrict__ rstd, const float* __restrict__ gamma,
                                const float* __restrict__ beta, bf16* __restrict__ xn) {
    const size_t n4 = (size_t)NPIX * C_ / 4;
    for (size_t i4 = (size_t)blockIdx.x * blockDim.x + threadIdx.x; i4 < n4;
         i4 += (size_t)gridDim.x * blockDim.x) {
        size_t e = i4 * 4;
        int cc = (int)(e & (C_ - 1));
        int bg = (int)(e >> 19) * G_ + (cc >> 4);   // 2^19 elements per batch
        float m = mean[bg], rs = rstd[bg];
        float4 t = *(const float4*)(x + e);
        __align__(8) bf16 o[4];
        o[0] = __float2bfloat16((t.x - m) * rs * gamma[cc + 0] + beta[cc + 0]);
        o[1] = __float2bfloat16((t.y - m) * rs * gamma[cc + 1] + beta[cc + 1]);
        o[2] = __float2bfloat16((t.z - m) * rs * gamma[cc + 2] + beta[cc + 2]);
        o[3] = __float2bfloat16((t.w - m) * rs * gamma[cc + 3] + beta[cc + 3]);
        *(ushort4*)(xn + e) = *(ushort4*)o;
    }
}

// ---------------- bf16 64x64 tiled transpose (batched): out[c][r] = in[r][c] ---
__global__ void transpose_kernel(const bf16* __restrict__ in, bf16* __restrict__ out,
                                 int R, int Cc) {
    __shared__ bf16 tile[64][65];
    size_t boff = (size_t)blockIdx.z * R * Cc;
    const bf16* src = in + boff;
    bf16* dst = out + boff;
    int c0 = blockIdx.x * 64, r0 = blockIdx.y * 64;
    int tx = threadIdx.x, ty = threadIdx.y;            // block (64, 4)
    for (int i = 0; i < 64; i += 4)
        tile[ty + i][tx] = src[(size_t)(r0 + ty + i) * Cc + c0 + tx];
    __syncthreads();
    for (int i = 0; i < 64; i += 4)
        dst[(size_t)(c0 + ty + i) * R + r0 + tx] = tile[tx][ty + i];
}

// ---------------- batched MFMA GEMM, m97 structure -----------------------------
// C[m][n] = sum_k A[m][k] * Bt[n][k].  128x128 tile, BK=32, 4 waves (2x2).
// global_load_lds width-16 into LINEAR LDS [128][32]; source-side XOR slot
// swizzle slot ^= (row>>1)&3 (conflict-free per 8-lane phase) + matching read.
// Grid total MUST be a multiple of 8 (bijective XCD swizzle).
// OUT_MODE: 3 f32+bias+residual, 4 fused-QKV bf16+bias,
//           5 P=exp(scale*s) bf16 + atomic row sums, 6 bf16 * (1/lsum[col])
template<int OUT_MODE>
__global__ __launch_bounds__(256) void gemm_kernel(
    const bf16* __restrict__ A, const bf16* __restrict__ Bt, void* __restrict__ Cv,
    const float* __restrict__ bias, const float* __restrict__ aux,
    int M, int N, int K, float scale,
    long long strideA, long long strideB, long long strideC)
{
    __shared__ __align__(16) ushort la[128 * 32];
    __shared__ __align__(16) ushort lb[128 * 32];

    // bijective XCD swizzle: each XCD gets a contiguous orig-range
    int gx = gridDim.x, gy = gridDim.y;
    int nwg = gx * gy * (int)gridDim.z;
    int d = blockIdx.x + gx * (blockIdx.y + gy * blockIdx.z);
    int orig = (d & 7) * (nwg >> 3) + (d >> 3);
    int bx = orig % gx, rest = orig / gx;
    int by = rest % gy, bz = rest / gy;

    const bf16* Ab = A + (size_t)bz * strideA;
    const bf16* Bb = Bt + (size_t)bz * strideB;
    int m0 = by * 128, n0 = bx * 128;
    int t = threadIdx.x;
    int wv = t >> 6, lane = t & 63;
    int wm = wv >> 1, wn = wv & 1;          // 2x2 waves, 64x64 each
    int lrow = lane & 15, kg = lane >> 4;
    int slot8 = (kg ^ ((lrow >> 1) & 3)) << 3;  // swizzled read slot (ushorts)

    // staging: wave wv stages chunks {2wv, 2wv+1} (16 rows each) of A and B
    int srow = lane >> 2;                       // row within 16-row chunk
    int gslot = (lane & 3) ^ ((srow >> 1) & 3); // inverse-swizzled global k-slot
    long long arow0 = (long long)(m0 + wv * 32 + srow) * K + gslot * 8;
    long long brow0 = (long long)(n0 + wv * 32 + srow) * K + gslot * 8;

    f32x4 acc[4][4] = {};

    for (int k0 = 0; k0 < K; k0 += 32) {
        #pragma unroll
        for (int cc = 0; cc < 2; ++cc) {
            gload16(Ab + arow0 + (long long)cc * 16 * K + k0, (char*)la + (wv * 2 + cc) * 1024);
            gload16(Bb + brow0 + (long long)cc * 16 * K + k0, (char*)lb + (wv * 2 + cc) * 1024);
        }
        __syncthreads();
        bf16x8 af[4], bg[4];
        #pragma unroll
        for (int f = 0; f < 4; ++f) {
            af[f] = *(const bf16x8*)&la[(wm * 64 + f * 16 + lrow) * 32 + slot8];
            bg[f] = *(const bf16x8*)&lb[(wn * 64 + f * 16 + lrow) * 32 + slot8];
        }
        #pragma unroll
        for (int i = 0; i < 4; ++i)
            #pragma unroll
            for (int j = 0; j < 4; ++j)
                acc[i][j] = __builtin_amdgcn_mfma_f32_16x16x32_bf16(af[i], bg[j], acc[i][j], 0, 0, 0);
        __syncthreads();
    }

    int rg = lane >> 4, ccol = lane & 15;

    if (OUT_MODE == 5) {
        // P = exp(scale*s) bf16 (no max-sub: |s*scale| <~ 8, clamp for safety)
        // + per-row partial sums atomically added to aux-as-lsum[bz*1024+row]
        float rowsum[16];
        #pragma unroll
        for (int u = 0; u < 16; ++u) rowsum[u] = 0.f;
        #pragma unroll
        for (int i = 0; i < 4; ++i)
            #pragma unroll
            for (int j = 0; j < 4; ++j) {
                int gcol = n0 + wn * 64 + j * 16 + ccol;
                int rowb = m0 + wm * 64 + i * 16 + rg * 4;
                #pragma unroll
                for (int r = 0; r < 4; ++r) {
                    float e = __expf(fminf(acc[i][j][r] * scale, 60.f));
                    rowsum[i * 4 + r] += e;
                    ((bf16*)Cv)[(size_t)bz * strideC + (size_t)(rowb + r) * N + gcol] =
                        __float2bfloat16(e);
                }
            }
        #pragma unroll
        for (int off = 1; off < 16; off <<= 1)
            #pragma unroll
            for (int u = 0; u < 16; ++u) rowsum[u] += __shfl_xor(rowsum[u], off);
        float* lsum = (float*)aux;
        #pragma unroll
        for (int u = 0; u < 16; ++u)
            if (ccol == u) {
                int row = m0 + wm * 64 + (u >> 2) * 16 + rg * 4 + (u & 3);
                atomicAdd(&lsum[(size_t)bz * 1024 + row], rowsum[u]);
            }
        return;
    }

    float linv[4];
    if (OUT_MODE == 6) {
        const float* lsum = aux;
        #pragma unroll
        for (int j = 0; j < 4; ++j)
            linv[j] = 1.f / lsum[(size_t)bz * 1024 + n0 + wn * 64 + j * 16 + ccol];
    }

    #pragma unroll
    for (int i = 0; i < 4; ++i)
        #pragma unroll
        for (int j = 0; j < 4; ++j) {
            int gcol = n0 + wn * 64 + j * 16 + ccol;
            int grow_base = m0 + wm * 64 + i * 16 + rg * 4;
            #pragma unroll
            for (int r = 0; r < 4; ++r) {
                float v = acc[i][j][r];
                if (OUT_MODE == 4) {
                    // fused QKV: col 0-511 -> q, 512-1023 -> k, 1024-1535 -> v
                    size_t idx = (size_t)(gcol >> 9) * ((size_t)NPIX * C_)
                               + (size_t)(grow_base + r) * C_ + (gcol & 511);
                    ((bf16*)Cv)[idx] = __float2bfloat16(v + bias[gcol]);
                } else {
                    size_t idx = (size_t)bz * strideC + (size_t)(grow_base + r) * N + gcol;
                    if (OUT_MODE == 6)      ((bf16*)Cv)[idx] = __float2bfloat16(v * linv[j]);
                    else                    ((float*)Cv)[idx] = v + bias[gcol] + ((const float*)aux)[idx];
                }
            }
        }
}

extern "C" void kernel_launch(void* const* d_in, const int* in_sizes, int n_in,
                              void* d_out, int out_size, void* d_ws, size_t ws_size,
                              hipStream_t stream) {
    const float* x     = (const float*)d_in[0];
    const float* gamma = (const float*)d_in[1];
    const float* beta  = (const float*)d_in[2];
    const float* wq    = (const float*)d_in[3];
    const float* bq    = (const float*)d_in[4];
    const float* wk    = (const float*)d_in[5];
    const float* bk    = (const float*)d_in[6];
    const float* wv    = (const float*)d_in[7];
    const float* bv    = (const float*)d_in[8];
    const float* wo    = (const float*)d_in[9];
    const float* bo    = (const float*)d_in[10];
    float* out = (float*)d_out;

    char* ws = (char*)d_ws;
    const size_t MB = 1ull << 20;
    bf16*  Wt   = (bf16*)ws;                    // [0,2) MB: 4x 512x512 bf16 (transposed)
    float* mean = (float*)(ws + 2 * MB);        // stats
    float* rstd = mean + 1024;
    float* bqkv = (float*)(ws + 2 * MB + 16384);// 1536 floats fused bias
    float* lsum = (float*)(ws + 3 * MB);        // 32x1024 fp32 row sums
    bf16*  xn   = (bf16*)(ws + 4 * MB);         // [4,36)
    bf16*  q    = (bf16*)(ws + 36 * MB);        // [36,68)   } q,k,v contiguous
    bf16*  k    = (bf16*)(ws + 68 * MB);        // [68,100)  } (fused QKV writes
    bf16*  v    = (bf16*)(ws + 100 * MB);       // [100,132) }  all three)
    bf16*  qt   = (bf16*)(ws + 132 * MB);       // [132,164)
    bf16*  kt   = (bf16*)(ws + 164 * MB);       // [164,196)
    bf16*  P    = (bf16*)(ws + 36 * MB);        // alias q,k (dead after transposes)
    bf16*  outr = (bf16*)(ws + 132 * MB);       // alias qt (dead after S)

    const long long SB = 524288;                // per-batch elements (1024*512)
    const long long SS = 1048576;               // per-batch S/P elements
    const float scale = 0.04419417382415922f;   // 512^-0.5

    hipMemsetAsync(lsum, 0, 32 * 1024 * sizeof(float), stream);
    wt_kernel<<<dim3(16, 16, 4), dim3(32, 8), 0, stream>>>(wq, wk, wv, wo, Wt);
    biascat_kernel<<<6, 256, 0, stream>>>(bq, bk, bv, bqkv);
    gn_stats_kernel<<<1024, 256, 0, stream>>>(x, mean, rstd);
    gn_apply_kernel<<<4096, 256, 0, stream>>>(x, mean, rstd, gamma, beta, xn);

    // fused QKV projection: (32768 x 512) @ (512 x 1536), split-writes q,k,v
    gemm_kernel<4><<<dim3(12, 256, 1), 256, 0, stream>>>(
        xn, Wt, q, bqkv, nullptr, NPIX, 1536, C_, 1.f, 0, 0, 0);

    // per-batch flat view (512,1024) -> transposed (1024,512) for S operands
    transpose_kernel<<<dim3(16, 8, 32), dim3(64, 4), 0, stream>>>(q, qt, 512, 1024);
    transpose_kernel<<<dim3(16, 8, 32), dim3(64, 4), 0, stream>>>(k, kt, 512, 1024);

    // P = exp(scale * Qr^T Kr) bf16 + row sums lsum (all 32 batches, one dispatch)
    gemm_kernel<5><<<dim3(8, 8, 32), 256, 0, stream>>>(
        qt, kt, P, nullptr, lsum, 1024, 1024, 512, scale, SB, SB, SS);

    // Out_r[i][j1] = (sum_j2 Vr[i][j2] * P[j1][j2]) / lsum[j1]
    gemm_kernel<6><<<dim3(8, 4, 32), 256, 0, stream>>>(
        v, P, outr, nullptr, lsum, 512, 1024, 1024, 1.f, SB, SS, SB);

    // final projection + bias + residual, fp32 out
    gemm_kernel<3><<<dim3(4, 256, 1), 256, 0, stream>>>(
        outr, Wt + 3 * C_ * C_, out, bo, x, NPIX, C_, C_, 1.f, 0, 0, 0);
}

// Round 5
// 409.287 us; speedup vs baseline: 1.3255x; 1.0988x over previous
//
#include <hip/hip_runtime.h>
#include <hip/hip_bf16.h>

#define B_   32
#define HW_  1024
#define C_   512
#define G_   32
#define CG_  16
#define NPIX (B_*HW_)   // 32768

typedef short bf16x8 __attribute__((ext_vector_type(8)));
typedef float f32x4  __attribute__((ext_vector_type(4)));
using bf16 = __hip_bfloat16;

// async global->LDS, 16B per lane; LDS dest = wave-uniform base + lane*16
__device__ __forceinline__ void gload16(const void* g, void* l) {
    __builtin_amdgcn_global_load_lds((const __attribute__((address_space(1))) void*)g,
                                     (__attribute__((address_space(3))) void*)l, 16, 0, 0);
}

// ---------------- weight transpose + bf16 convert: Wt[d][c] = bf16(w[c][d]) ----
__global__ void wt_kernel(const float* __restrict__ w0, const float* __restrict__ w1,
                          const float* __restrict__ w2, const float* __restrict__ w3,
                          bf16* __restrict__ out) {
    __shared__ float tile[32][33];
    const float* src = blockIdx.z == 0 ? w0 : blockIdx.z == 1 ? w1 : blockIdx.z == 2 ? w2 : w3;
    bf16* dst = out + (size_t)blockIdx.z * C_ * C_;
    int r0 = blockIdx.y * 32, c0 = blockIdx.x * 32;
    int tx = threadIdx.x, ty = threadIdx.y;            // block (32, 8)
    for (int i = 0; i < 32; i += 8)
        tile[ty + i][tx] = src[(size_t)(r0 + ty + i) * C_ + c0 + tx];
    __syncthreads();
    for (int i = 0; i < 32; i += 8)
        dst[(size_t)(c0 + ty + i) * C_ + r0 + tx] = __float2bfloat16(tile[tx][ty + i]);
}

// ---------------- concat bias: [bq | bk | bv] -> 1536 floats -------------------
__global__ void biascat_kernel(const float* __restrict__ bq, const float* __restrict__ bk,
                               const float* __restrict__ bv, float* __restrict__ o) {
    int i = blockIdx.x * 256 + threadIdx.x;            // grid 6 x 256
    const float* s = i < 512 ? bq : i < 1024 ? bk : bv;
    o[i] = s[i & 511];
}

// ---------------- GroupNorm stats: one block per (batch, group) ----------------
__global__ void gn_stats_kernel(const float* __restrict__ x, float* __restrict__ mean,
                                float* __restrict__ rstd) {
    int b = blockIdx.x >> 5, g = blockIdx.x & 31;
    const float* xp = x + (size_t)b * HW_ * C_ + g * CG_;
    float s = 0.f, ss = 0.f;
    for (int p = threadIdx.x; p < HW_; p += 256) {
        const float4* v = (const float4*)(xp + (size_t)p * C_);
        #pragma unroll
        for (int j = 0; j < 4; ++j) {
            float4 t = v[j];
            s  += t.x + t.y + t.z + t.w;
            ss += t.x*t.x + t.y*t.y + t.z*t.z + t.w*t.w;
        }
    }
    #pragma unroll
    for (int off = 32; off; off >>= 1) { s += __shfl_down(s, off); ss += __shfl_down(ss, off); }
    __shared__ float red[2][4];
    int lane = threadIdx.x & 63, wv = threadIdx.x >> 6;
    if (lane == 0) { red[0][wv] = s; red[1][wv] = ss; }
    __syncthreads();
    if (threadIdx.x == 0) {
        float S  = red[0][0] + red[0][1] + red[0][2] + red[0][3];
        float SS = red[1][0] + red[1][1] + red[1][2] + red[1][3];
        const float inv_n = 1.f / (HW_ * CG_);
        float m = S * inv_n;
        float var = SS * inv_n - m * m;
        mean[blockIdx.x] = m;
        rstd[blockIdx.x] = rsqrtf(var + 1e-6f);
    }
}

// ---------------- GroupNorm apply + bf16 convert -------------------------------
__global__ void gn_apply_kernel(const float* __restrict__ x, const float* __restrict__ mean,
                                const float* __restrict__ rstd, const float* __restrict__ gamma,
                                const float* __restrict__ beta, bf16* __restrict__ xn) {
    const size_t n4 = (size_t)NPIX * C_ / 4;
    for (size_t i4 = (size_t)blockIdx.x * blockDim.x + threadIdx.x; i4 < n4;
         i4 += (size_t)gridDim.x * blockDim.x) {
        size_t e = i4 * 4;
        int cc = (int)(e & (C_ - 1));
        int bg = (int)(e >> 19) * G_ + (cc >> 4);   // 2^19 elements per batch
        float m = mean[bg], rs = rstd[bg];
        float4 t = *(const float4*)(x + e);
        __align__(8) bf16 o[4];
        o[0] = __float2bfloat16((t.x - m) * rs * gamma[cc + 0] + beta[cc + 0]);
        o[1] = __float2bfloat16((t.y - m) * rs * gamma[cc + 1] + beta[cc + 1]);
        o[2] = __float2bfloat16((t.z - m) * rs * gamma[cc + 2] + beta[cc + 2]);
        o[3] = __float2bfloat16((t.w - m) * rs * gamma[cc + 3] + beta[cc + 3]);
        *(ushort4*)(xn + e) = *(ushort4*)o;
    }
}

// ---------------- bf16 64x64 tiled transpose (batched): out[c][r] = in[r][c] ---
__global__ void transpose_kernel(const bf16* __restrict__ in, bf16* __restrict__ out,
                                 int R, int Cc) {
    __shared__ bf16 tile[64][65];
    size_t boff = (size_t)blockIdx.z * R * Cc;
    const bf16* src = in + boff;
    bf16* dst = out + boff;
    int c0 = blockIdx.x * 64, r0 = blockIdx.y * 64;
    int tx = threadIdx.x, ty = threadIdx.y;            // block (64, 4)
    for (int i = 0; i < 64; i += 4)
        tile[ty + i][tx] = src[(size_t)(r0 + ty + i) * Cc + c0 + tx];
    __syncthreads();
    for (int i = 0; i < 64; i += 4)
        dst[(size_t)(c0 + ty + i) * R + r0 + tx] = tile[tx][ty + i];
}

// ---------------- batched MFMA GEMM, 2-phase double-buffered pipeline ----------
// C[m][n] = sum_k A[m][k] * Bt[n][k].  128x128 tile, BK=32 x2 buffers, 4 waves.
// T3-min schedule: STAGE(next) issued at region start overlaps ds_read+MFMA of
// cur; single __syncthreads (vmcnt(0)+barrier) per K-step. T5 setprio on MFMA.
// LDS linear per-buffer [128][32] ushort; source-side XOR slot swizzle
// slot ^= (row>>1)&3 + matching swizzled ds_read (conflict-free, verified r4).
// Grid total MUST be a multiple of 8 (bijective XCD swizzle). K % 64 == 0.
// OUT_MODE: 3 f32+bias+residual, 4 fused-QKV bf16+bias,
//           5 P=exp(scale*s) bf16 + atomic row sums, 6 bf16 * (1/lsum[col])
template<int OUT_MODE>
__global__ __launch_bounds__(256) void gemm_kernel(
    const bf16* __restrict__ A, const bf16* __restrict__ Bt, void* __restrict__ Cv,
    const float* __restrict__ bias, const float* __restrict__ aux,
    int M, int N, int K, float scale,
    long long strideA, long long strideB, long long strideC)
{
    __shared__ __align__(16) ushort la0[4096], lb0[4096];
    __shared__ __align__(16) ushort la1[4096], lb1[4096];

    // bijective XCD swizzle: each XCD gets a contiguous orig-range
    int gx = gridDim.x, gy = gridDim.y;
    int nwg = gx * gy * (int)gridDim.z;
    int d = blockIdx.x + gx * (blockIdx.y + gy * blockIdx.z);
    int orig = (d & 7) * (nwg >> 3) + (d >> 3);
    int bx = orig % gx, rest = orig / gx;
    int by = rest % gy, bz = rest / gy;

    const bf16* Ab = A + (size_t)bz * strideA;
    const bf16* Bb = Bt + (size_t)bz * strideB;
    int m0 = by * 128, n0 = bx * 128;
    int t = threadIdx.x;
    int wv = t >> 6, lane = t & 63;
    int wm = wv >> 1, wn = wv & 1;          // 2x2 waves, 64x64 each
    int lrow = lane & 15, kg = lane >> 4;
    int slot8 = (kg ^ ((lrow >> 1) & 3)) << 3;  // swizzled read slot (ushorts)

    // staging: wave wv stages chunks {2wv, 2wv+1} (16 rows each) of A and B
    int srow = lane >> 2;                       // row within 16-row chunk
    int gslot = (lane & 3) ^ ((srow >> 1) & 3); // inverse-swizzled global k-slot
    long long arow0 = (long long)(m0 + wv * 32 + srow) * K + gslot * 8;
    long long brow0 = (long long)(n0 + wv * 32 + srow) * K + gslot * 8;

    f32x4 acc[4][4] = {};

    auto stage = [&](ushort* La, ushort* Lb, int k0) {
        #pragma unroll
        for (int cc = 0; cc < 2; ++cc) {
            gload16(Ab + arow0 + (long long)cc * 16 * K + k0, (char*)La + (wv * 2 + cc) * 1024);
            gload16(Bb + brow0 + (long long)cc * 16 * K + k0, (char*)Lb + (wv * 2 + cc) * 1024);
        }
    };
    auto compute = [&](const ushort* La, const ushort* Lb) {
        bf16x8 af[4], bg[4];
        #pragma unroll
        for (int f = 0; f < 4; ++f) {
            af[f] = *(const bf16x8*)&La[(wm * 64 + f * 16 + lrow) * 32 + slot8];
            bg[f] = *(const bf16x8*)&Lb[(wn * 64 + f * 16 + lrow) * 32 + slot8];
        }
        __builtin_amdgcn_s_setprio(1);
        #pragma unroll
        for (int i = 0; i < 4; ++i)
            #pragma unroll
            for (int j = 0; j < 4; ++j)
                acc[i][j] = __builtin_amdgcn_mfma_f32_16x16x32_bf16(af[i], bg[j], acc[i][j], 0, 0, 0);
        __builtin_amdgcn_s_setprio(0);
    };

    stage(la0, lb0, 0);
    __syncthreads();                            // vmcnt(0) + barrier: tile 0 ready
    for (int k0 = 0; k0 < K; k0 += 64) {
        if (k0 + 32 < K) stage(la1, lb1, k0 + 32);   // overlaps compute below
        compute(la0, lb0);
        __syncthreads();                        // drains stage; barrier
        if (k0 + 64 < K) stage(la0, lb0, k0 + 64);
        compute(la1, lb1);
        __syncthreads();
    }

    int rg = lane >> 4, ccol = lane & 15;

    if (OUT_MODE == 5) {
        // P = exp(scale*s) bf16 (no max-sub: |s*scale| <~ 8, clamp for safety)
        // + per-row partial sums atomically added to aux-as-lsum[bz*1024+row]
        float rowsum[16];
        #pragma unroll
        for (int u = 0; u < 16; ++u) rowsum[u] = 0.f;
        #pragma unroll
        for (int i = 0; i < 4; ++i)
            #pragma unroll
            for (int j = 0; j < 4; ++j) {
                int gcol = n0 + wn * 64 + j * 16 + ccol;
                int rowb = m0 + wm * 64 + i * 16 + rg * 4;
                #pragma unroll
                for (int r = 0; r < 4; ++r) {
                    float e = __expf(fminf(acc[i][j][r] * scale, 60.f));
                    rowsum[i * 4 + r] += e;
                    ((bf16*)Cv)[(size_t)bz * strideC + (size_t)(rowb + r) * N + gcol] =
                        __float2bfloat16(e);
                }
            }
        #pragma unroll
        for (int off = 1; off < 16; off <<= 1)
            #pragma unroll
            for (int u = 0; u < 16; ++u) rowsum[u] += __shfl_xor(rowsum[u], off);
        float* lsum = (float*)aux;
        #pragma unroll
        for (int u = 0; u < 16; ++u)
            if (ccol == u) {
                int row = m0 + wm * 64 + (u >> 2) * 16 + rg * 4 + (u & 3);
                atomicAdd(&lsum[(size_t)bz * 1024 + row], rowsum[u]);
            }
        return;
    }

    float linv[4];
    if (OUT_MODE == 6) {
        const float* lsum = aux;
        #pragma unroll
        for (int j = 0; j < 4; ++j)
            linv[j] = 1.f / lsum[(size_t)bz * 1024 + n0 + wn * 64 + j * 16 + ccol];
    }

    #pragma unroll
    for (int i = 0; i < 4; ++i)
        #pragma unroll
        for (int j = 0; j < 4; ++j) {
            int gcol = n0 + wn * 64 + j * 16 + ccol;
            int grow_base = m0 + wm * 64 + i * 16 + rg * 4;
            #pragma unroll
            for (int r = 0; r < 4; ++r) {
                float v = acc[i][j][r];
                if (OUT_MODE == 4) {
                    // fused QKV: col 0-511 -> q, 512-1023 -> k, 1024-1535 -> v
                    size_t idx = (size_t)(gcol >> 9) * ((size_t)NPIX * C_)
                               + (size_t)(grow_base + r) * C_ + (gcol & 511);
                    ((bf16*)Cv)[idx] = __float2bfloat16(v + bias[gcol]);
                } else {
                    size_t idx = (size_t)bz * strideC + (size_t)(grow_base + r) * N + gcol;
                    if (OUT_MODE == 6)      ((bf16*)Cv)[idx] = __float2bfloat16(v * linv[j]);
                    else                    ((float*)Cv)[idx] = v + bias[gcol] + ((const float*)aux)[idx];
                }
            }
        }
}

extern "C" void kernel_launch(void* const* d_in, const int* in_sizes, int n_in,
                              void* d_out, int out_size, void* d_ws, size_t ws_size,
                              hipStream_t stream) {
    const float* x     = (const float*)d_in[0];
    const float* gamma = (const float*)d_in[1];
    const float* beta  = (const float*)d_in[2];
    const float* wq    = (const float*)d_in[3];
    const float* bq    = (const float*)d_in[4];
    const float* wk    = (const float*)d_in[5];
    const float* bk    = (const float*)d_in[6];
    const float* wv    = (const float*)d_in[7];
    const float* bv    = (const float*)d_in[8];
    const float* wo    = (const float*)d_in[9];
    const float* bo    = (const float*)d_in[10];
    float* out = (float*)d_out;

    char* ws = (char*)d_ws;
    const size_t MB = 1ull << 20;
    bf16*  Wt   = (bf16*)ws;                    // [0,2) MB: 4x 512x512 bf16 (transposed)
    float* mean = (float*)(ws + 2 * MB);        // stats
    float* rstd = mean + 1024;
    float* bqkv = (float*)(ws + 2 * MB + 16384);// 1536 floats fused bias
    float* lsum = (float*)(ws + 3 * MB);        // 32x1024 fp32 row sums
    bf16*  xn   = (bf16*)(ws + 4 * MB);         // [4,36)
    bf16*  q    = (bf16*)(ws + 36 * MB);        // [36,68)   } q,k,v contiguous
    bf16*  k    = (bf16*)(ws + 68 * MB);        // [68,100)  } (fused QKV writes
    bf16*  v    = (bf16*)(ws + 100 * MB);       // [100,132) }  all three)
    bf16*  qt   = (bf16*)(ws + 132 * MB);       // [132,164)
    bf16*  kt   = (bf16*)(ws + 164 * MB);       // [164,196)
    bf16*  P    = (bf16*)(ws + 36 * MB);        // alias q,k (dead after transposes)
    bf16*  outr = (bf16*)(ws + 132 * MB);       // alias qt (dead after S)

    const long long SB = 524288;                // per-batch elements (1024*512)
    const long long SS = 1048576;               // per-batch S/P elements
    const float scale = 0.04419417382415922f;   // 512^-0.5

    hipMemsetAsync(lsum, 0, 32 * 1024 * sizeof(float), stream);
    wt_kernel<<<dim3(16, 16, 4), dim3(32, 8), 0, stream>>>(wq, wk, wv, wo, Wt);
    biascat_kernel<<<6, 256, 0, stream>>>(bq, bk, bv, bqkv);
    gn_stats_kernel<<<1024, 256, 0, stream>>>(x, mean, rstd);
    gn_apply_kernel<<<4096, 256, 0, stream>>>(x, mean, rstd, gamma, beta, xn);

    // fused QKV projection: (32768 x 512) @ (512 x 1536), split-writes q,k,v
    gemm_kernel<4><<<dim3(12, 256, 1), 256, 0, stream>>>(
        xn, Wt, q, bqkv, nullptr, NPIX, 1536, C_, 1.f, 0, 0, 0);

    // per-batch flat view (512,1024) -> transposed (1024,512) for S operands
    transpose_kernel<<<dim3(16, 8, 32), dim3(64, 4), 0, stream>>>(q, qt, 512, 1024);
    transpose_kernel<<<dim3(16, 8, 32), dim3(64, 4), 0, stream>>>(k, kt, 512, 1024);

    // P = exp(scale * Qr^T Kr) bf16 + row sums lsum (all 32 batches, one dispatch)
    gemm_kernel<5><<<dim3(8, 8, 32), 256, 0, stream>>>(
        qt, kt, P, nullptr, lsum, 1024, 1024, 512, scale, SB, SB, SS);

    // Out_r[i][j1] = (sum_j2 Vr[i][j2] * P[j1][j2]) / lsum[j1]
    gemm_kernel<6><<<dim3(8, 4, 32), 256, 0, stream>>>(
        v, P, outr, nullptr, lsum, 512, 1024, 1024, 1.f, SB, SS, SB);

    // final projection + bias + residual, fp32 out
    gemm_kernel<3><<<dim3(4, 256, 1), 256, 0, stream>>>(
        outr, Wt + 3 * C_ * C_, out, bo, x, NPIX, C_, C_, 1.f, 0, 0, 0);
}

// Round 6
// 395.762 us; speedup vs baseline: 1.3708x; 1.0342x over previous
//
#include <hip/hip_runtime.h>
#include <hip/hip_bf16.h>

#define B_   32
#define HW_  1024
#define C_   512
#define G_   32
#define CG_  16
#define NPIX (B_*HW_)   // 32768

typedef short bf16x8 __attribute__((ext_vector_type(8)));
typedef float f32x4  __attribute__((ext_vector_type(4)));
using bf16 = __hip_bfloat16;

// async global->LDS, 16B per lane; LDS dest = wave-uniform base + lane*16
__device__ __forceinline__ void gload16(const void* g, void* l) {
    __builtin_amdgcn_global_load_lds((const __attribute__((address_space(1))) void*)g,
                                     (__attribute__((address_space(3))) void*)l, 16, 0, 0);
}

// ---------------- weight transpose + bf16 convert: Wt[d][c] = bf16(w[c][d]) ----
__global__ void wt_kernel(const float* __restrict__ w0, const float* __restrict__ w1,
                          const float* __restrict__ w2, const float* __restrict__ w3,
                          bf16* __restrict__ out) {
    __shared__ float tile[32][33];
    const float* src = blockIdx.z == 0 ? w0 : blockIdx.z == 1 ? w1 : blockIdx.z == 2 ? w2 : w3;
    bf16* dst = out + (size_t)blockIdx.z * C_ * C_;
    int r0 = blockIdx.y * 32, c0 = blockIdx.x * 32;
    int tx = threadIdx.x, ty = threadIdx.y;            // block (32, 8)
    for (int i = 0; i < 32; i += 8)
        tile[ty + i][tx] = src[(size_t)(r0 + ty + i) * C_ + c0 + tx];
    __syncthreads();
    for (int i = 0; i < 32; i += 8)
        dst[(size_t)(c0 + ty + i) * C_ + r0 + tx] = __float2bfloat16(tile[tx][ty + i]);
}

// ---------------- concat bias: [bq | bk | bv] -> 1536 floats -------------------
__global__ void biascat_kernel(const float* __restrict__ bq, const float* __restrict__ bk,
                               const float* __restrict__ bv, float* __restrict__ o) {
    int i = blockIdx.x * 256 + threadIdx.x;            // grid 6 x 256
    const float* s = i < 512 ? bq : i < 1024 ? bk : bv;
    o[i] = s[i & 511];
}

// ---------------- GroupNorm stats: one block per (batch, group) ----------------
__global__ void gn_stats_kernel(const float* __restrict__ x, float* __restrict__ mean,
                                float* __restrict__ rstd) {
    int b = blockIdx.x >> 5, g = blockIdx.x & 31;
    const float* xp = x + (size_t)b * HW_ * C_ + g * CG_;
    float s = 0.f, ss = 0.f;
    for (int p = threadIdx.x; p < HW_; p += 256) {
        const float4* v = (const float4*)(xp + (size_t)p * C_);
        #pragma unroll
        for (int j = 0; j < 4; ++j) {
            float4 t = v[j];
            s  += t.x + t.y + t.z + t.w;
            ss += t.x*t.x + t.y*t.y + t.z*t.z + t.w*t.w;
        }
    }
    #pragma unroll
    for (int off = 32; off; off >>= 1) { s += __shfl_down(s, off); ss += __shfl_down(ss, off); }
    __shared__ float red[2][4];
    int lane = threadIdx.x & 63, wv = threadIdx.x >> 6;
    if (lane == 0) { red[0][wv] = s; red[1][wv] = ss; }
    __syncthreads();
    if (threadIdx.x == 0) {
        float S  = red[0][0] + red[0][1] + red[0][2] + red[0][3];
        float SS = red[1][0] + red[1][1] + red[1][2] + red[1][3];
        const float inv_n = 1.f / (HW_ * CG_);
        float m = S * inv_n;
        float var = SS * inv_n - m * m;
        mean[blockIdx.x] = m;
        rstd[blockIdx.x] = rsqrtf(var + 1e-6f);
    }
}

// ---------------- GroupNorm apply + bf16 convert -------------------------------
__global__ void gn_apply_kernel(const float* __restrict__ x, const float* __restrict__ mean,
                                const float* __restrict__ rstd, const float* __restrict__ gamma,
                                const float* __restrict__ beta, bf16* __restrict__ xn) {
    const size_t n4 = (size_t)NPIX * C_ / 4;
    for (size_t i4 = (size_t)blockIdx.x * blockDim.x + threadIdx.x; i4 < n4;
         i4 += (size_t)gridDim.x * blockDim.x) {
        size_t e = i4 * 4;
        int cc = (int)(e & (C_ - 1));
        int bg = (int)(e >> 19) * G_ + (cc >> 4);   // 2^19 elements per batch
        float m = mean[bg], rs = rstd[bg];
        float4 t = *(const float4*)(x + e);
        __align__(8) bf16 o[4];
        o[0] = __float2bfloat16((t.x - m) * rs * gamma[cc + 0] + beta[cc + 0]);
        o[1] = __float2bfloat16((t.y - m) * rs * gamma[cc + 1] + beta[cc + 1]);
        o[2] = __float2bfloat16((t.z - m) * rs * gamma[cc + 2] + beta[cc + 2]);
        o[3] = __float2bfloat16((t.w - m) * rs * gamma[cc + 3] + beta[cc + 3]);
        *(ushort4*)(xn + e) = *(ushort4*)o;
    }
}

// ---------------- bf16 64x64 tiled transpose (batched): out[c][r] = in[r][c] ---
__global__ void transpose_kernel(const bf16* __restrict__ in, bf16* __restrict__ out,
                                 int R, int Cc) {
    __shared__ bf16 tile[64][65];
    size_t boff = (size_t)blockIdx.z * R * Cc;
    const bf16* src = in + boff;
    bf16* dst = out + boff;
    int c0 = blockIdx.x * 64, r0 = blockIdx.y * 64;
    int tx = threadIdx.x, ty = threadIdx.y;            // block (64, 4)
    for (int i = 0; i < 64; i += 4)
        tile[ty + i][tx] = src[(size_t)(r0 + ty + i) * Cc + c0 + tx];
    __syncthreads();
    for (int i = 0; i < 64; i += 4)
        dst[(size_t)(c0 + ty + i) * R + r0 + tx] = tile[tx][ty + i];
}

// ---------------- batched MFMA GEMM, 256x256 8-phase pipeline ------------------
// C[m][n] = sum_k A[m][k]*Bt[n][k]. BK=64, 2 K-tile buffers, 8 waves (2m x 4n),
// per-wave 128x64 out (acc[8][4]). LDS [buf][half][128][64] per operand,
// XOR slot-swizzle (slot ^= row&7): stage source pre-swizzled, reads swizzled.
// Schedule per iter (tiles T0=2i buf0, T1=2i+1 buf1); phase =
//   [vmcnt @ph1/ph5] barrier; stage 1 half; ds_read frags; lgkm0; setprio MFMA.
//   ph1: A-lo(T0)+B0(T0) reads, MMA lo*B0, stage A-h0(T1),  vmcnt(4)
//   ph2: B1(T0) reads,          MMA lo*B1, stage A-h1(T1)
//   ph3: A-hi(T0) reads,        MMA hi*B1, stage B-h0(T2)
//   ph4: no reads,              MMA hi*B0, stage B-h1(T2)
//   ph5-8: same on T1/buf1, staging A(T2) ph5/6, B(T3) ph7/8, vmcnt(4)@ph5
//   (last iter: stages T2/T3 skipped, ph5 uses vmcnt(0))
// Ledger: every stage targets a region last READ >=1 barrier earlier; every
// read is covered by a boundary vmcnt >=1 barrier earlier. Grid %8==0.
// OUT_MODE: 3 f32+bias+residual, 4 fused-QKV bf16+bias,
//           5 P=exp(scale*s) bf16 + atomic row sums, 6 bf16 * (1/lsum[col])
template<int OUT_MODE>
__global__ __launch_bounds__(512, 2) void gemm_kernel(
    const bf16* __restrict__ A, const bf16* __restrict__ Bt, void* __restrict__ Cv,
    const float* __restrict__ bias, const float* __restrict__ aux,
    int M, int N, int K, float scale,
    long long strideA, long long strideB, long long strideC)
{
    __shared__ __align__(16) ushort ldsA[2][2][8192];   // [buf][half][128*64]
    __shared__ __align__(16) ushort ldsB[2][2][8192];

    // bijective XCD swizzle
    int gx = gridDim.x, gy = gridDim.y;
    int nwg = gx * gy * (int)gridDim.z;
    int d = blockIdx.x + gx * (blockIdx.y + gy * blockIdx.z);
    int orig = (d & 7) * (nwg >> 3) + (d >> 3);
    int bx = orig % gx, rest = orig / gx;
    int by = rest % gy, bz = rest / gy;

    const bf16* Ab = A + (size_t)bz * strideA;
    const bf16* Bb = Bt + (size_t)bz * strideB;
    int m0 = by * 256, n0 = bx * 256;
    int t = threadIdx.x;
    int wv8 = t >> 6, lane = t & 63;
    int wm = wv8 >> 2, wn = wv8 & 3;            // 2x4 waves, 128x64 each
    int lrow = lane & 15, kg = lane >> 4;
    int rsw = lrow & 7;

    // staging: thread covers (row = tid>>3 [+64], slot = tid&7), source slot
    // inverse-swizzled so linear DMA + swizzled read = consistent (rule 21)
    long long soff = (long long)(t >> 3) * K + (((t & 7) ^ ((t >> 3) & 7)) << 3);
    long long aoff = (long long)m0 * K + soff;
    long long boff = (long long)n0 * K + soff;
    int ldsbyte = wv8 * 1024;

    f32x4 acc[8][4] = {};
    bf16x8 afq[4][2], bg0[2][2], bg1[2][2];

    auto stA = [&](int buf, int half, int kt) {
        const bf16* g = Ab + aoff + (long long)half * 128 * K + (long long)kt * 64;
        char* l = (char*)&ldsA[buf][half][0] + ldsbyte;
        gload16(g, l);
        gload16(g + 64ll * K, l + 8192);
    };
    auto stB = [&](int buf, int half, int kt) {
        const bf16* g = Bb + boff + (long long)half * 128 * K + (long long)kt * 64;
        char* l = (char*)&ldsB[buf][half][0] + ldsbyte;
        gload16(g, l);
        gload16(g + 64ll * K, l + 8192);
    };
    auto ldA = [&](int buf, int f0) {
        const char* base = (const char*)&ldsA[buf][wm][0];
        #pragma unroll
        for (int f = 0; f < 4; ++f) {
            int row = (f0 + f) * 16 + lrow;
            #pragma unroll
            for (int ks = 0; ks < 2; ++ks)
                afq[f][ks] = *(const bf16x8*)(base + row * 128 + (((ks * 4 + kg) ^ rsw) << 4));
        }
    };
    auto ldB = [&](int buf, int c0, bf16x8 (&bg)[2][2]) {
        const char* base = (const char*)&ldsB[buf][wn >> 1][0];
        #pragma unroll
        for (int c = 0; c < 2; ++c) {
            int col = (wn & 1) * 64 + (c0 + c) * 16 + lrow;
            #pragma unroll
            for (int ks = 0; ks < 2; ++ks)
                bg[c][ks] = *(const bf16x8*)(base + col * 128 + (((ks * 4 + kg) ^ rsw) << 4));
        }
    };
    auto mma = [&](int fb, int cb, bf16x8 (&bg)[2][2]) {
        __builtin_amdgcn_s_setprio(1);
        #pragma unroll
        for (int f = 0; f < 4; ++f)
            #pragma unroll
            for (int c = 0; c < 2; ++c)
                #pragma unroll
                for (int ks = 0; ks < 2; ++ks)
                    acc[fb + f][cb + c] = __builtin_amdgcn_mfma_f32_16x16x32_bf16(
                        afq[f][ks], bg[c][ks], acc[fb + f][cb + c], 0, 0, 0);
        __builtin_amdgcn_s_setprio(0);
    };

#define BAR()    __builtin_amdgcn_s_barrier()
#define LGKM0()  do { asm volatile("s_waitcnt lgkmcnt(0)" ::: "memory"); \
                      __builtin_amdgcn_sched_barrier(0); } while (0)
#define VM(n)    asm volatile("s_waitcnt vmcnt(" #n ")" ::: "memory")

    // prologue: B(0), A(0), B(1) halves (6 halves = 12 loads)
    stB(0, 0, 0); stB(0, 1, 0); stA(0, 0, 0); stA(0, 1, 0);
    stB(1, 0, 1); stB(1, 1, 1);

    int nkt = K >> 6, iters = nkt >> 1;
    for (int i = 0; i < iters; ++i) {
        int t1 = 2 * i + 1, t2 = 2 * i + 2, t3 = 2 * i + 3;
        bool more = (i + 1 < iters);
        // ph1
        VM(4); BAR();
        stA(1, 0, t1);
        ldA(0, 0); ldB(0, 0, bg0);
        LGKM0();
        mma(0, 0, bg0);
        // ph2
        BAR();
        stA(1, 1, t1);
        ldB(0, 2, bg1);
        LGKM0();
        mma(0, 2, bg1);
        // ph3
        BAR();
        if (more) stB(0, 0, t2);
        ldA(0, 4);
        LGKM0();
        mma(4, 2, bg1);
        // ph4
        BAR();
        if (more) stB(0, 1, t2);
        __builtin_amdgcn_sched_barrier(0);
        mma(4, 0, bg0);
        // ph5
        if (more) VM(4); else VM(0);
        BAR();
        if (more) stA(0, 0, t2);
        ldA(1, 0); ldB(1, 0, bg0);
        LGKM0();
        mma(0, 0, bg0);
        // ph6
        BAR();
        if (more) stA(0, 1, t2);
        ldB(1, 2, bg1);
        LGKM0();
        mma(0, 2, bg1);
        // ph7
        BAR();
        if (more) stB(1, 0, t3);
        ldA(1, 4);
        LGKM0();
        mma(4, 2, bg1);
        // ph8
        BAR();
        if (more) stB(1, 1, t3);
        __builtin_amdgcn_sched_barrier(0);
        mma(4, 0, bg0);
    }

    int rg = lane >> 4, ccol = lane & 15;

    if (OUT_MODE == 5) {
        // P = exp(scale*s) bf16 (no max-sub: |s*scale| small, clamp for safety)
        // + per-row partial sums atomically added to lsum[bz*1024+row]
        float rowsum[32];
        #pragma unroll
        for (int u = 0; u < 32; ++u) rowsum[u] = 0.f;
        #pragma unroll
        for (int i = 0; i < 8; ++i)
            #pragma unroll
            for (int j = 0; j < 4; ++j) {
                int gcol = n0 + wn * 64 + j * 16 + ccol;
                int rowb = m0 + wm * 128 + i * 16 + rg * 4;
                #pragma unroll
                for (int r = 0; r < 4; ++r) {
                    float e = __expf(fminf(acc[i][j][r] * scale, 60.f));
                    rowsum[i * 4 + r] += e;
                    ((bf16*)Cv)[(size_t)bz * strideC + (size_t)(rowb + r) * N + gcol] =
                        __float2bfloat16(e);
                }
            }
        #pragma unroll
        for (int off = 1; off < 16; off <<= 1)
            #pragma unroll
            for (int u = 0; u < 32; ++u) rowsum[u] += __shfl_xor(rowsum[u], off);
        float* lsum = (float*)aux;
        #pragma unroll
        for (int u = 0; u < 32; ++u)
            if (ccol == (u & 15)) {
                int row = m0 + wm * 128 + (u >> 2) * 16 + rg * 4 + (u & 3);
                atomicAdd(&lsum[(size_t)bz * 1024 + row], rowsum[u]);
            }
        return;
    }

    float linv[4];
    if (OUT_MODE == 6) {
        const float* lsum = aux;
        #pragma unroll
        for (int j = 0; j < 4; ++j)
            linv[j] = 1.f / lsum[(size_t)bz * 1024 + n0 + wn * 64 + j * 16 + ccol];
    }

    #pragma unroll
    for (int i = 0; i < 8; ++i)
        #pragma unroll
        for (int j = 0; j < 4; ++j) {
            int gcol = n0 + wn * 64 + j * 16 + ccol;
            int grow_base = m0 + wm * 128 + i * 16 + rg * 4;
            #pragma unroll
            for (int r = 0; r < 4; ++r) {
                float v = acc[i][j][r];
                if (OUT_MODE == 4) {
                    // fused QKV: col 0-511 -> q, 512-1023 -> k, 1024-1535 -> v
                    size_t idx = (size_t)(gcol >> 9) * ((size_t)NPIX * C_)
                               + (size_t)(grow_base + r) * C_ + (gcol & 511);
                    ((bf16*)Cv)[idx] = __float2bfloat16(v + bias[gcol]);
                } else {
                    size_t idx = (size_t)bz * strideC + (size_t)(grow_base + r) * N + gcol;
                    if (OUT_MODE == 6)      ((bf16*)Cv)[idx] = __float2bfloat16(v * linv[j]);
                    else                    ((float*)Cv)[idx] = v + bias[gcol] + ((const float*)aux)[idx];
                }
            }
        }
#undef BAR
#undef LGKM0
#undef VM
}

extern "C" void kernel_launch(void* const* d_in, const int* in_sizes, int n_in,
                              void* d_out, int out_size, void* d_ws, size_t ws_size,
                              hipStream_t stream) {
    const float* x     = (const float*)d_in[0];
    const float* gamma = (const float*)d_in[1];
    const float* beta  = (const float*)d_in[2];
    const float* wq    = (const float*)d_in[3];
    const float* bq    = (const float*)d_in[4];
    const float* wk    = (const float*)d_in[5];
    const float* bk    = (const float*)d_in[6];
    const float* wv    = (const float*)d_in[7];
    const float* bv    = (const float*)d_in[8];
    const float* wo    = (const float*)d_in[9];
    const float* bo    = (const float*)d_in[10];
    float* out = (float*)d_out;

    char* ws = (char*)d_ws;
    const size_t MB = 1ull << 20;
    bf16*  Wt   = (bf16*)ws;                    // [0,2) MB: 4x 512x512 bf16 (transposed)
    float* mean = (float*)(ws + 2 * MB);        // stats
    float* rstd = mean + 1024;
    float* bqkv = (float*)(ws + 2 * MB + 16384);// 1536 floats fused bias
    float* lsum = (float*)(ws + 3 * MB);        // 32x1024 fp32 row sums
    bf16*  xn   = (bf16*)(ws + 4 * MB);         // [4,36)
    bf16*  q    = (bf16*)(ws + 36 * MB);        // [36,68)   } q,k,v contiguous
    bf16*  k    = (bf16*)(ws + 68 * MB);        // [68,100)  } (fused QKV writes
    bf16*  v    = (bf16*)(ws + 100 * MB);       // [100,132) }  all three)
    bf16*  qt   = (bf16*)(ws + 132 * MB);       // [132,164)
    bf16*  kt   = (bf16*)(ws + 164 * MB);       // [164,196)
    bf16*  P    = (bf16*)(ws + 36 * MB);        // alias q,k (dead after transposes)
    bf16*  outr = (bf16*)(ws + 132 * MB);       // alias qt (dead after S)

    const long long SB = 524288;                // per-batch elements (1024*512)
    const long long SS = 1048576;               // per-batch S/P elements
    const float scale = 0.04419417382415922f;   // 512^-0.5

    hipMemsetAsync(lsum, 0, 32 * 1024 * sizeof(float), stream);
    wt_kernel<<<dim3(16, 16, 4), dim3(32, 8), 0, stream>>>(wq, wk, wv, wo, Wt);
    biascat_kernel<<<6, 256, 0, stream>>>(bq, bk, bv, bqkv);
    gn_stats_kernel<<<1024, 256, 0, stream>>>(x, mean, rstd);
    gn_apply_kernel<<<4096, 256, 0, stream>>>(x, mean, rstd, gamma, beta, xn);

    // fused QKV projection: (32768 x 512) @ (512 x 1536), split-writes q,k,v
    gemm_kernel<4><<<dim3(6, 128, 1), 512, 0, stream>>>(
        xn, Wt, q, bqkv, nullptr, NPIX, 1536, C_, 1.f, 0, 0, 0);

    // per-batch flat view (512,1024) -> transposed (1024,512) for S operands
    transpose_kernel<<<dim3(16, 8, 32), dim3(64, 4), 0, stream>>>(q, qt, 512, 1024);
    transpose_kernel<<<dim3(16, 8, 32), dim3(64, 4), 0, stream>>>(k, kt, 512, 1024);

    // P = exp(scale * Qr^T Kr) bf16 + row sums lsum (all 32 batches)
    gemm_kernel<5><<<dim3(4, 4, 32), 512, 0, stream>>>(
        qt, kt, P, nullptr, lsum, 1024, 1024, 512, scale, SB, SB, SS);

    // Out_r[i][j1] = (sum_j2 Vr[i][j2] * P[j1][j2]) / lsum[j1]
    gemm_kernel<6><<<dim3(4, 2, 32), 512, 0, stream>>>(
        v, P, outr, nullptr, lsum, 512, 1024, 1024, 1.f, SB, SS, SB);

    // final projection + bias + residual, fp32 out
    gemm_kernel<3><<<dim3(2, 128, 1), 512, 0, stream>>>(
        outr, Wt + 3 * C_ * C_, out, bo, x, NPIX, C_, C_, 1.f, 0, 0, 0);
}